// Round 7
// baseline (603.694 us; speedup 1.0000x reference)
//
#include <hip/hip_runtime.h>
#include <hip/hip_fp16.h>
#include <cstdint>
#include <cstddef>

#define N_NODES 100000
#define N_EDGES 1600000
#define D 128
#define NLAYERS 3
#define NB 3125       // buckets of 32 nodes
#define NBLK_E 128    // edge-phase blocks
#define EPB 12500     // edges per block: 1600000/128
#define ENT_CAP 1024  // fill2 LDS entries; bucket max ~600 (22 sigma)
#define NPAN 8        // feature panels (16 feats each), pinned to XCDs via blockIdx%8

// ---------------- CSR build: LDS-histogram counting sort (no global atomics) ----------------

__global__ __launch_bounds__(512) void hist1_kernel(const int* __restrict__ col,
                                                    int* __restrict__ hmat) {
    __shared__ int hist[NB];
    int b = blockIdx.x, t = threadIdx.x;
    for (int j = t; j < NB; j += 512) hist[j] = 0;
    __syncthreads();
    const int4* col4 = (const int4*)(col + b * EPB);
    for (int i = t; i < EPB / 4; i += 512) {
        int4 c = col4[i];
        atomicAdd(&hist[c.x >> 5], 1);
        atomicAdd(&hist[c.y >> 5], 1);
        atomicAdd(&hist[c.z >> 5], 1);
        atomicAdd(&hist[c.w >> 5], 1);
    }
    __syncthreads();
    for (int j = t; j < NB; j += 512) hmat[b * NB + j] = hist[j];
}

__global__ void btot_kernel(const int* __restrict__ hmat, int* __restrict__ btot) {
    int j = blockIdx.x * 256 + threadIdx.x;
    if (j < NB) {
        int s = 0;
        for (int b = 0; b < NBLK_E; b++) s += hmat[b * NB + j];
        btot[j] = s;
    }
}

// Single-block exclusive scan over 3125 bucket totals -> bstart (+ sentinel).
__global__ void bscan_kernel(const int* __restrict__ btot, int* __restrict__ bstart, int nb, int e) {
    __shared__ int lsum[1024];
    int t = threadIdx.x;
    int vals[4];
    int v0 = 0;
#pragma unroll
    for (int j = 0; j < 4; j++) {
        int idx = t * 4 + j;
        int c = (idx < nb) ? btot[idx] : 0;
        vals[j] = c;
        v0 += c;
    }
    lsum[t] = v0;
    __syncthreads();
    for (int off = 1; off < 1024; off <<= 1) {
        int x = (t >= off) ? lsum[t - off] : 0;
        __syncthreads();
        lsum[t] += x;
        __syncthreads();
    }
    int base = lsum[t] - v0;  // exclusive
#pragma unroll
    for (int j = 0; j < 4; j++) {
        int idx = t * 4 + j;
        if (idx < nb) {
            bstart[idx] = base;
            base += vals[j];
        }
    }
    if (t == 0) bstart[nb] = e;
}

// Per-(block,bucket) start offsets: hoff[b][j] = bstart[j] + sum_{b'<b} hmat[b'][j]
__global__ void hoff_kernel(const int* __restrict__ hmat, const int* __restrict__ bstart,
                            int* __restrict__ hoff) {
    int j = blockIdx.x * 256 + threadIdx.x;
    if (j < NB) {
        int run = bstart[j];
        for (int b = 0; b < NBLK_E; b++) {
            hoff[b * NB + j] = run;
            run += hmat[b * NB + j];
        }
    }
}

// Scatter edges to exact bucket-sorted positions. LDS cursors, no global atomics.
__global__ __launch_bounds__(512) void scatter_kernel(const int* __restrict__ row,
                                                      const int* __restrict__ col,
                                                      const int* __restrict__ hoff,
                                                      unsigned* __restrict__ bucketbuf) {
    __shared__ int cur[NB];
    int b = blockIdx.x, t = threadIdx.x;
    for (int j = t; j < NB; j += 512) cur[j] = hoff[b * NB + j];
    __syncthreads();
    int base = b * EPB;
    for (int i = t; i < EPB; i += 512) {
        int r = row[base + i], c = col[base + i];
        int pos = atomicAdd(&cur[c >> 5], 1);  // LDS atomic
        bucketbuf[pos] = ((unsigned)r << 5) | (unsigned)(c & 31);
    }
}

// One block per bucket: LDS histogram of 32 local cols -> per-node offsets,
// dinv, and localized CSR scatter (contiguous ~2KB range, LDS cursors).
__global__ void fill2_kernel(const unsigned* __restrict__ bucketbuf, const int* __restrict__ bstart,
                             int* __restrict__ offsets, float* __restrict__ dinv,
                             int* __restrict__ src, int n, int e) {
    __shared__ unsigned ent[ENT_CAP];
    __shared__ int hist[32];
    __shared__ int cur[32];
    __shared__ int loff[32];
    int b = blockIdx.x, t = threadIdx.x;
    int s0 = bstart[b];
    int cnt = bstart[b + 1] - s0;
    if (cnt > ENT_CAP) cnt = ENT_CAP;
    if (t < 32) hist[t] = 0;
    __syncthreads();
    for (int i = t; i < cnt; i += 256) {
        unsigned v = bucketbuf[s0 + i];
        ent[i] = v;
        atomicAdd(&hist[v & 31], 1);
    }
    __syncthreads();
    if (t == 0) {
        int run = s0;
#pragma unroll
        for (int j = 0; j < 32; j++) {
            loff[j] = run;
            run += hist[j];
        }
    }
    __syncthreads();
    if (t < 32) {
        int node = b * 32 + t;
        int o = loff[t];
        offsets[node] = o;
        cur[t] = o;
        dinv[node] = rsqrtf((float)(hist[t] + 1));  // +1 self loop
    }
    if (b == 0 && t == 0) offsets[n] = e;
    __syncthreads();
    for (int i = t; i < cnt; i += 256) {
        unsigned v = ent[i];
        int pos = atomicAdd(&cur[v & 31], 1);
        src[pos] = (int)(v >> 5);
    }
}

// ---------------- per-layer kernels ----------------

// Stage xs[v] = dinv[v]*x[v] as fp16 in PANEL-MAJOR layout: xhp[p][node][16 feats].
// Panel slice = 3.2 MB -> fits one XCD's 4 MB L2 when panel is pinned via blockIdx%8.
__global__ void cast_panel_kernel(const float2* __restrict__ in, const float* __restrict__ dinv,
                                  __half2* __restrict__ xhp) {
    int i = blockIdx.x * 256 + threadIdx.x;  // [0, N_NODES*8)
    int p = blockIdx.y;
    int v = i >> 3, f2 = i & 7;
    float dv = dinv[v];
    float2 val = in[(size_t)v * 64 + p * 8 + f2];
    xhp[((size_t)p * N_NODES + v) * 8 + f2] = __floats2half2_rn(dv * val.x, dv * val.y);
}

// Panel-partitioned aggregation. Block = 32 dst nodes x 1 panel (16 feats);
// panel = blockIdx%8 pins each panel's 3.2 MB gather set to one XCD's L2.
// 8 lanes per node, half2 per lane (32 B/group coalesced gathers), serial edges,
// src window + offsets + dinv staged in LDS. out[v] = dinv[v]*(xs[v]+sum xs[src]).
__global__ __launch_bounds__(256) void agg_panel_kernel(const __half2* __restrict__ xhp,
                                                        const int* __restrict__ offs,
                                                        const int* __restrict__ src,
                                                        const float* __restrict__ dinv,
                                                        float* __restrict__ out) {
    __shared__ int sedge[1024];
    __shared__ int soff[33];
    __shared__ float sdv[32];
    int blk = blockIdx.x;
    int p = blk & 7;          // panel; consecutive blocks -> different XCDs (round-robin)
    int v0 = (blk >> 3) * 32;
    int t = threadIdx.x;
    if (t < 33) soff[t] = offs[v0 + t];
    if (t >= 64 && t < 96) sdv[t - 64] = dinv[v0 + (t - 64)];
    __syncthreads();
    int e0 = soff[0];
    int cnt = soff[32] - e0;
    int lim = cnt < 1024 ? cnt : 1024;
    for (int i = t; i < lim; i += 256) sedge[i] = src[e0 + i];
    __syncthreads();

    int lane = t & 63;
    int g = lane >> 3, f2 = lane & 7;
    int vl = (t >> 6) * 8 + g;     // local node 0..31
    int v = v0 + vl;
    const __half2* xp = xhp + (size_t)p * (N_NODES * 8);

    int o0 = soff[vl] - e0, o1 = soff[vl + 1] - e0;
    float2 acc = __half22float2(xp[(size_t)v * 8 + f2]);  // self term (prescaled)

    int iend = o1 < lim ? o1 : lim;
    int i = o0;
    for (; i + 1 < iend; i += 2) {
        int sA = sedge[i], sB = sedge[i + 1];
        float2 a = __half22float2(xp[(size_t)sA * 8 + f2]);
        float2 b = __half22float2(xp[(size_t)sB * 8 + f2]);
        acc.x += a.x + b.x;
        acc.y += a.y + b.y;
    }
    if (i < iend) {
        float2 a = __half22float2(xp[(size_t)sedge[i] * 8 + f2]);
        acc.x += a.x;
        acc.y += a.y;
    }
    // overflow path (cnt > 1024: ~22 sigma, correctness only)
    for (int j = (o0 > lim ? o0 : lim); j < o1; j++) {
        float2 a = __half22float2(xp[(size_t)src[e0 + j] * 8 + f2]);
        acc.x += a.x;
        acc.y += a.y;
    }

    float dv = sdv[vl];
    float2 w;
    w.x = dv * acc.x;
    w.y = dv * acc.y;
    ((float2*)out)[(size_t)v * 64 + p * 8 + f2] = w;
}

// out[M x 128] = relu(A[M x 128] @ W[128 x 128] + bias), 32 rows per block,
// W staged in LDS (64 KB), k-vectorized float4 inner loop.
// Optionally writes the dinv-prescaled fp16 PANEL-MAJOR copy for the next layer.
__global__ __launch_bounds__(256, 2) void gemm_bias_relu_kernel(
    const float* __restrict__ A, const float* __restrict__ W,
    const float* __restrict__ bias, const float* __restrict__ dinv,
    float* __restrict__ out, __half2* __restrict__ xhp_out, int write_h) {
    __shared__ float sW[128 * 128];  // 64 KB
    __shared__ float sX[32 * 128];   // 16 KB
    int t = threadIdx.x;
    int tx = t & 31;   // 32 col-groups of 4
    int ty = t >> 5;   // 8 row-groups of 4
    int row0 = blockIdx.x * 32;

    const float4* W4 = (const float4*)W;
    float4* sW4 = (float4*)sW;
#pragma unroll
    for (int i = 0; i < 16; i++) sW4[t + 256 * i] = W4[t + 256 * i];

    const float4* A4 = (const float4*)A;
    float4* sX4 = (float4*)sX;
#pragma unroll
    for (int i = 0; i < 4; i++) {
        int c = t + 256 * i;
        int r = c >> 5, kc = c & 31;
        sX4[r * 32 + kc] = A4[(size_t)(row0 + r) * 32 + kc];
    }
    __syncthreads();

    float4 acc[4];
#pragma unroll
    for (int r = 0; r < 4; r++) acc[r] = make_float4(0.f, 0.f, 0.f, 0.f);

#define FMA4(a, s, b) a.x += (s) * (b).x; a.y += (s) * (b).y; a.z += (s) * (b).z; a.w += (s) * (b).w;
#pragma unroll 4
    for (int k0 = 0; k0 < 128; k0 += 4) {
        float4 b0 = *(const float4*)&sW[(k0 + 0) * 128 + tx * 4];
        float4 b1 = *(const float4*)&sW[(k0 + 1) * 128 + tx * 4];
        float4 b2 = *(const float4*)&sW[(k0 + 2) * 128 + tx * 4];
        float4 b3 = *(const float4*)&sW[(k0 + 3) * 128 + tx * 4];
#pragma unroll
        for (int r = 0; r < 4; r++) {
            float4 a = *(const float4*)&sX[(ty * 4 + r) * 128 + k0];
            FMA4(acc[r], a.x, b0)
            FMA4(acc[r], a.y, b1)
            FMA4(acc[r], a.z, b2)
            FMA4(acc[r], a.w, b3)
        }
    }
#undef FMA4

    float4 bb = ((const float4*)bias)[tx];
#pragma unroll
    for (int r = 0; r < 4; r++) {
        float4 o;
        o.x = fmaxf(acc[r].x + bb.x, 0.0f);
        o.y = fmaxf(acc[r].y + bb.y, 0.0f);
        o.z = fmaxf(acc[r].z + bb.z, 0.0f);
        o.w = fmaxf(acc[r].w + bb.w, 0.0f);
        size_t rowi = (size_t)(row0 + ty * 4 + r);
        ((float4*)out)[rowi * 32 + tx] = o;
        if (write_h) {
            float dv = dinv[rowi];
            int pp = tx >> 2;  // panel of cols tx*4..tx*4+3
            size_t base = ((size_t)pp * N_NODES + rowi) * 8 + (tx & 3) * 2;
            xhp_out[base] = __floats2half2_rn(dv * o.x, dv * o.y);
            xhp_out[base + 1] = __floats2half2_rn(dv * o.z, dv * o.w);
        }
    }
}

// ---------------- launch ----------------

extern "C" void kernel_launch(void* const* d_in, const int* in_sizes, int n_in,
                              void* d_out, int out_size, void* d_ws, size_t ws_size,
                              hipStream_t stream) {
    const int* edge = (const int*)d_in[0];   // [2, E] int32
    const float* emb = (const float*)d_in[1];
    const float* Ws = (const float*)d_in[2]; // [L, D, D]
    const float* bs = (const float*)d_in[3]; // [L, D]
    float* out = (float*)d_out;

    const int n = N_NODES, e = N_EDGES;
    const int* row = edge;       // sources
    const int* col = edge + e;   // targets

    char* p = (char*)d_ws;
    float* aggbuf = (float*)p;
    int* hmat = (int*)p;                      // aliases aggbuf (dead until first agg)
    int* hoff = hmat + (size_t)NBLK_E * NB;
    p += (size_t)n * D * 4;                   // 51.2 MB
    __half2* xhp = (__half2*)p;               // 25.6 MB (panel-major prescaled fp16)
    unsigned* bucketbuf = (unsigned*)p;       // aliases xhp: dead before cast runs
    p += (size_t)n * D * 2;
    int* csr_src  = (int*)p;    p += (size_t)e * 4;           // 6.4 MB
    float* dinv   = (float*)p;  p += (size_t)n * 4;
    int* offsets  = (int*)p;    p += (size_t)(n + 1) * 4;
    int* btot     = (int*)p;    p += (size_t)NB * 4;
    int* bstart   = (int*)p;    p += (size_t)(NB + 1) * 4;

    hist1_kernel<<<NBLK_E, 512, 0, stream>>>(col, hmat);
    btot_kernel<<<(NB + 255) / 256, 256, 0, stream>>>(hmat, btot);
    bscan_kernel<<<1, 1024, 0, stream>>>(btot, bstart, NB, e);
    hoff_kernel<<<(NB + 255) / 256, 256, 0, stream>>>(hmat, bstart, hoff);
    scatter_kernel<<<NBLK_E, 512, 0, stream>>>(row, col, hoff, bucketbuf);
    fill2_kernel<<<NB, 256, 0, stream>>>(bucketbuf, bstart, offsets, dinv, csr_src, n, e);

    dim3 cgrid(n * 8 / 256, 8);  // 3125 x 8
    cast_panel_kernel<<<cgrid, 256, 0, stream>>>((const float2*)emb, dinv, xhp);

    for (int l = 0; l < NLAYERS; l++) {
        agg_panel_kernel<<<(n / 32) * NPAN, 256, 0, stream>>>(xhp, offsets, csr_src, dinv, aggbuf);
        gemm_bias_relu_kernel<<<n / 32, 256, 0, stream>>>(
            aggbuf, Ws + (size_t)l * D * D, bs + (size_t)l * D, dinv, out,
            xhp, (l < NLAYERS - 1) ? 1 : 0);
    }
}

// Round 8
// 587.224 us; speedup vs baseline: 1.0280x; 1.0280x over previous
//
#include <hip/hip_runtime.h>
#include <hip/hip_fp16.h>
#include <cstdint>
#include <cstddef>

#define N_NODES 100000
#define N_EDGES 1600000
#define D 128
#define NLAYERS 3
#define NB 3125       // buckets of 32 nodes
#define NBLK_E 500    // edge-phase blocks (~2 blocks/CU)
#define EPB 3200      // edges per block: 1600000/500
#define ENT_CAP 1024  // agg LDS edge window; bucket max ~600 (22 sigma)
#define NPAN 8        // feature panels (16 feats = 32 B each), pinned to XCDs via blockIdx%8

typedef __attribute__((ext_vector_type(8))) _Float16 half8;

// ---------------- CSR build: LDS-histogram counting sort (no global atomics) ----------------

__global__ __launch_bounds__(512) void hist1_kernel(const int* __restrict__ col,
                                                    int* __restrict__ hmat) {
    __shared__ int hist[NB];
    int b = blockIdx.x, t = threadIdx.x;
    for (int j = t; j < NB; j += 512) hist[j] = 0;
    __syncthreads();
    const int4* col4 = (const int4*)(col + b * EPB);
    for (int i = t; i < EPB / 4; i += 512) {
        int4 c = col4[i];
        atomicAdd(&hist[c.x >> 5], 1);
        atomicAdd(&hist[c.y >> 5], 1);
        atomicAdd(&hist[c.z >> 5], 1);
        atomicAdd(&hist[c.w >> 5], 1);
    }
    __syncthreads();
    for (int j = t; j < NB; j += 512) hmat[b * NB + j] = hist[j];
}

__global__ void btot_kernel(const int* __restrict__ hmat, int* __restrict__ btot) {
    int j = blockIdx.x * 256 + threadIdx.x;
    if (j < NB) {
        int s = 0;
        for (int b = 0; b < NBLK_E; b++) s += hmat[b * NB + j];
        btot[j] = s;
    }
}

// Single-block exclusive scan over 3125 bucket totals -> bstart (+ sentinel).
__global__ void bscan_kernel(const int* __restrict__ btot, int* __restrict__ bstart, int nb, int e) {
    __shared__ int lsum[1024];
    int t = threadIdx.x;
    int vals[4];
    int v0 = 0;
#pragma unroll
    for (int j = 0; j < 4; j++) {
        int idx = t * 4 + j;
        int c = (idx < nb) ? btot[idx] : 0;
        vals[j] = c;
        v0 += c;
    }
    lsum[t] = v0;
    __syncthreads();
    for (int off = 1; off < 1024; off <<= 1) {
        int x = (t >= off) ? lsum[t - off] : 0;
        __syncthreads();
        lsum[t] += x;
        __syncthreads();
    }
    int base = lsum[t] - v0;  // exclusive
#pragma unroll
    for (int j = 0; j < 4; j++) {
        int idx = t * 4 + j;
        if (idx < nb) {
            bstart[idx] = base;
            base += vals[j];
        }
    }
    if (t == 0) bstart[nb] = e;
}

// Per-(block,bucket) start offsets: hoff[b][j] = bstart[j] + sum_{b'<b} hmat[b'][j]
__global__ void hoff_kernel(const int* __restrict__ hmat, const int* __restrict__ bstart,
                            int* __restrict__ hoff) {
    int j = blockIdx.x * 256 + threadIdx.x;
    if (j < NB) {
        int run = bstart[j];
        for (int b = 0; b < NBLK_E; b++) {
            hoff[b * NB + j] = run;
            run += hmat[b * NB + j];
        }
    }
}

// Scatter edges to exact bucket-sorted positions. LDS cursors, no global atomics.
__global__ __launch_bounds__(512) void scatter_kernel(const int* __restrict__ row,
                                                      const int* __restrict__ col,
                                                      const int* __restrict__ hoff,
                                                      unsigned* __restrict__ bucketbuf) {
    __shared__ int cur[NB];
    int b = blockIdx.x, t = threadIdx.x;
    for (int j = t; j < NB; j += 512) cur[j] = hoff[b * NB + j];
    __syncthreads();
    int base = b * EPB;
    for (int i = t; i < EPB; i += 512) {
        int r = row[base + i], c = col[base + i];
        int pos = atomicAdd(&cur[c >> 5], 1);  // LDS atomic
        bucketbuf[pos] = ((unsigned)r << 5) | (unsigned)(c & 31);
    }
}

// One block per bucket: LDS histogram of 32 local cols -> per-node offsets,
// dinv, and localized CSR scatter (contiguous ~2KB range, LDS cursors).
__global__ void fill2_kernel(const unsigned* __restrict__ bucketbuf, const int* __restrict__ bstart,
                             int* __restrict__ offsets, float* __restrict__ dinv,
                             int* __restrict__ src, int n, int e) {
    __shared__ unsigned ent[ENT_CAP];
    __shared__ int hist[32];
    __shared__ int cur[32];
    __shared__ int loff[32];
    int b = blockIdx.x, t = threadIdx.x;
    int s0 = bstart[b];
    int cnt = bstart[b + 1] - s0;
    if (cnt > ENT_CAP) cnt = ENT_CAP;
    if (t < 32) hist[t] = 0;
    __syncthreads();
    for (int i = t; i < cnt; i += 256) {
        unsigned v = bucketbuf[s0 + i];
        ent[i] = v;
        atomicAdd(&hist[v & 31], 1);
    }
    __syncthreads();
    if (t == 0) {
        int run = s0;
#pragma unroll
        for (int j = 0; j < 32; j++) {
            loff[j] = run;
            run += hist[j];
        }
    }
    __syncthreads();
    if (t < 32) {
        int node = b * 32 + t;
        int o = loff[t];
        offsets[node] = o;
        cur[t] = o;
        dinv[node] = rsqrtf((float)(hist[t] + 1));  // +1 self loop
    }
    if (b == 0 && t == 0) offsets[n] = e;
    __syncthreads();
    for (int i = t; i < cnt; i += 256) {
        unsigned v = ent[i];
        int pos = atomicAdd(&cur[v & 31], 1);
        src[pos] = (int)(v >> 5);
    }
}

// ---------------- per-layer kernels ----------------

// Stage xs[v] = dinv[v]*x[v] as fp16 in PANEL-MAJOR layout: xhp[p][node][16 feats].
// Panel slice = 3.2 MB -> fits one XCD's 4 MB L2 when panel is pinned via blockIdx%8.
__global__ void cast_panel_kernel(const float2* __restrict__ in, const float* __restrict__ dinv,
                                  __half2* __restrict__ xhp) {
    int i = blockIdx.x * 256 + threadIdx.x;  // [0, N_NODES*8)
    int p = blockIdx.y;
    int v = i >> 3, f2 = i & 7;
    float dv = dinv[v];
    float2 val = in[(size_t)v * 64 + p * 8 + f2];
    xhp[((size_t)p * N_NODES + v) * 8 + f2] = __floats2half2_rn(dv * val.x, dv * val.y);
}

// Panel-partitioned aggregation, 16 B/lane requests.
// Block = 32 dst nodes x 1 panel (16 feats = 32 B row); panel = blockIdx%8 pins
// the 3.2 MB panel slice to one XCD's L2 (verified R7: FETCH 192->71 MB).
// Per node: 8 lanes = 4 sub-groups x 2 lanes; each 2-lane group reads one edge's
// 32 B row as 2x half8 (16 B/lane) -> 32 edge-gathers per wave instr (1 KB/instr,
// 4x fewer instrs than R7), unroll 2 -> 8 gathers in flight per node.
__global__ __launch_bounds__(256) void agg_panel_kernel(const __half* __restrict__ xhp,
                                                        const int* __restrict__ offs,
                                                        const int* __restrict__ src,
                                                        const float* __restrict__ dinv,
                                                        float* __restrict__ out) {
    __shared__ int sedge[ENT_CAP];
    __shared__ int soff[33];
    __shared__ float sdv[32];
    int blk = blockIdx.x;
    int p = blk & 7;          // panel; consecutive blocks -> different XCDs (round-robin)
    int v0 = (blk >> 3) * 32;
    int t = threadIdx.x;
    if (t < 33) soff[t] = offs[v0 + t];
    if (t >= 64 && t < 96) sdv[t - 64] = dinv[v0 + (t - 64)];
    __syncthreads();
    int e0 = soff[0];
    int cnt = soff[32] - e0;
    int lim = cnt < ENT_CAP ? cnt : ENT_CAP;
    for (int i = t; i < lim; i += 256) sedge[i] = src[e0 + i];
    __syncthreads();

    int lane = t & 63;
    int vl = (t >> 6) * 8 + (lane >> 3);   // local node 0..31 (8 nodes per wave)
    int sub = (lane >> 1) & 3;             // 4 edge sub-streams per node
    int half = lane & 1;                   // which 16 B of the 32 B row
    int v = v0 + vl;
    const __half* xp = xhp + (size_t)p * ((size_t)N_NODES * 16) + half * 8;

    float acc[8] = {0.f, 0.f, 0.f, 0.f, 0.f, 0.f, 0.f, 0.f};
    if (sub == 0) {  // self term (prescaled); both halves covered by the 2 lanes
        half8 hv = *(const half8*)(xp + (size_t)v * 16);
#pragma unroll
        for (int j = 0; j < 8; j++) acc[j] += (float)hv[j];
    }

    int o0 = soff[vl] - e0, o1 = soff[vl + 1] - e0;
    int iend = o1 < lim ? o1 : lim;
    int i = o0 + sub;
    for (; i + 4 < iend; i += 8) {  // pair of gathers in flight per sub-stream
        int sA = sedge[i], sB = sedge[i + 4];
        half8 hA = *(const half8*)(xp + (size_t)sA * 16);
        half8 hB = *(const half8*)(xp + (size_t)sB * 16);
#pragma unroll
        for (int j = 0; j < 8; j++) acc[j] += (float)hA[j] + (float)hB[j];
    }
    for (; i < iend; i += 4) {
        half8 hA = *(const half8*)(xp + (size_t)sedge[i] * 16);
#pragma unroll
        for (int j = 0; j < 8; j++) acc[j] += (float)hA[j];
    }
    for (; i < o1; i += 4) {  // overflow (cnt > ENT_CAP: ~22 sigma, correctness only)
        half8 hA = *(const half8*)(xp + (size_t)src[e0 + i] * 16);
#pragma unroll
        for (int j = 0; j < 8; j++) acc[j] += (float)hA[j];
    }

    // combine the 4 sub-streams (lane distance 2 and 4 within the 8-lane node group)
#pragma unroll
    for (int j = 0; j < 8; j++) {
        acc[j] += __shfl_xor(acc[j], 2, 64);
        acc[j] += __shfl_xor(acc[j], 4, 64);
    }

    if (sub == 0) {  // 2 lanes/node write the panel's 64 B chunk (one full cache line)
        float dv = sdv[vl];
        float* dst = out + (size_t)v * 128 + p * 16 + half * 8;
        float4 w0, w1;
        w0.x = dv * acc[0]; w0.y = dv * acc[1]; w0.z = dv * acc[2]; w0.w = dv * acc[3];
        w1.x = dv * acc[4]; w1.y = dv * acc[5]; w1.z = dv * acc[6]; w1.w = dv * acc[7];
        *(float4*)dst = w0;
        *(float4*)(dst + 4) = w1;
    }
}

// out[M x 128] = relu(A[M x 128] @ W[128 x 128] + bias), 32 rows per block,
// W staged in LDS (64 KB), k-vectorized float4 inner loop.
// Optionally writes the dinv-prescaled fp16 PANEL-MAJOR copy for the next layer.
__global__ __launch_bounds__(256, 2) void gemm_bias_relu_kernel(
    const float* __restrict__ A, const float* __restrict__ W,
    const float* __restrict__ bias, const float* __restrict__ dinv,
    float* __restrict__ out, __half2* __restrict__ xhp_out, int write_h) {
    __shared__ float sW[128 * 128];  // 64 KB
    __shared__ float sX[32 * 128];   // 16 KB
    int t = threadIdx.x;
    int tx = t & 31;   // 32 col-groups of 4
    int ty = t >> 5;   // 8 row-groups of 4
    int row0 = blockIdx.x * 32;

    const float4* W4 = (const float4*)W;
    float4* sW4 = (float4*)sW;
#pragma unroll
    for (int i = 0; i < 16; i++) sW4[t + 256 * i] = W4[t + 256 * i];

    const float4* A4 = (const float4*)A;
    float4* sX4 = (float4*)sX;
#pragma unroll
    for (int i = 0; i < 4; i++) {
        int c = t + 256 * i;
        int r = c >> 5, kc = c & 31;
        sX4[r * 32 + kc] = A4[(size_t)(row0 + r) * 32 + kc];
    }
    __syncthreads();

    float4 acc[4];
#pragma unroll
    for (int r = 0; r < 4; r++) acc[r] = make_float4(0.f, 0.f, 0.f, 0.f);

#define FMA4(a, s, b) a.x += (s) * (b).x; a.y += (s) * (b).y; a.z += (s) * (b).z; a.w += (s) * (b).w;
#pragma unroll 4
    for (int k0 = 0; k0 < 128; k0 += 4) {
        float4 b0 = *(const float4*)&sW[(k0 + 0) * 128 + tx * 4];
        float4 b1 = *(const float4*)&sW[(k0 + 1) * 128 + tx * 4];
        float4 b2 = *(const float4*)&sW[(k0 + 2) * 128 + tx * 4];
        float4 b3 = *(const float4*)&sW[(k0 + 3) * 128 + tx * 4];
#pragma unroll
        for (int r = 0; r < 4; r++) {
            float4 a = *(const float4*)&sX[(ty * 4 + r) * 128 + k0];
            FMA4(acc[r], a.x, b0)
            FMA4(acc[r], a.y, b1)
            FMA4(acc[r], a.z, b2)
            FMA4(acc[r], a.w, b3)
        }
    }
#undef FMA4

    float4 bb = ((const float4*)bias)[tx];
#pragma unroll
    for (int r = 0; r < 4; r++) {
        float4 o;
        o.x = fmaxf(acc[r].x + bb.x, 0.0f);
        o.y = fmaxf(acc[r].y + bb.y, 0.0f);
        o.z = fmaxf(acc[r].z + bb.z, 0.0f);
        o.w = fmaxf(acc[r].w + bb.w, 0.0f);
        size_t rowi = (size_t)(row0 + ty * 4 + r);
        ((float4*)out)[rowi * 32 + tx] = o;
        if (write_h) {
            float dv = dinv[rowi];
            int pp = tx >> 2;  // panel of cols tx*4..tx*4+3
            size_t base = ((size_t)pp * N_NODES + rowi) * 8 + (tx & 3) * 2;
            xhp_out[base] = __floats2half2_rn(dv * o.x, dv * o.y);
            xhp_out[base + 1] = __floats2half2_rn(dv * o.z, dv * o.w);
        }
    }
}

// ---------------- launch ----------------

extern "C" void kernel_launch(void* const* d_in, const int* in_sizes, int n_in,
                              void* d_out, int out_size, void* d_ws, size_t ws_size,
                              hipStream_t stream) {
    const int* edge = (const int*)d_in[0];   // [2, E] int32
    const float* emb = (const float*)d_in[1];
    const float* Ws = (const float*)d_in[2]; // [L, D, D]
    const float* bs = (const float*)d_in[3]; // [L, D]
    float* out = (float*)d_out;

    const int n = N_NODES, e = N_EDGES;
    const int* row = edge;       // sources
    const int* col = edge + e;   // targets

    char* p = (char*)d_ws;
    float* aggbuf = (float*)p;
    int* hmat = (int*)p;                      // aliases aggbuf (dead until first agg)
    int* hoff = hmat + (size_t)NBLK_E * NB;   // 6.25 MB each, inside aggbuf's 51.2 MB
    p += (size_t)n * D * 4;                   // 51.2 MB
    __half2* xhp = (__half2*)p;               // 25.6 MB (panel-major prescaled fp16)
    unsigned* bucketbuf = (unsigned*)p;       // aliases xhp: dead before cast runs
    p += (size_t)n * D * 2;
    int* csr_src  = (int*)p;    p += (size_t)e * 4;           // 6.4 MB
    float* dinv   = (float*)p;  p += (size_t)n * 4;
    int* offsets  = (int*)p;    p += (size_t)(n + 1) * 4;
    int* btot     = (int*)p;    p += (size_t)NB * 4;
    int* bstart   = (int*)p;    p += (size_t)(NB + 1) * 4;

    hist1_kernel<<<NBLK_E, 512, 0, stream>>>(col, hmat);
    btot_kernel<<<(NB + 255) / 256, 256, 0, stream>>>(hmat, btot);
    bscan_kernel<<<1, 1024, 0, stream>>>(btot, bstart, NB, e);
    hoff_kernel<<<(NB + 255) / 256, 256, 0, stream>>>(hmat, bstart, hoff);
    scatter_kernel<<<NBLK_E, 512, 0, stream>>>(row, col, hoff, bucketbuf);
    fill2_kernel<<<NB, 256, 0, stream>>>(bucketbuf, bstart, offsets, dinv, csr_src, n, e);

    dim3 cgrid(n * 8 / 256, 8);  // 3125 x 8
    cast_panel_kernel<<<cgrid, 256, 0, stream>>>((const float2*)emb, dinv, xhp);

    for (int l = 0; l < NLAYERS; l++) {
        agg_panel_kernel<<<(n / 32) * NPAN, 256, 0, stream>>>(
            (const __half*)xhp, offsets, csr_src, dinv, aggbuf);
        gemm_bias_relu_kernel<<<n / 32, 256, 0, stream>>>(
            aggbuf, Ws + (size_t)l * D * D, bs + (size_t)l * D, dinv, out,
            xhp, (l < NLAYERS - 1) ? 1 : 0);
    }
}